// Round 7
// baseline (158.670 us; speedup 1.0000x reference)
//
#include <hip/hip_runtime.h>
#include <hip/hip_bf16.h>

#define B_    2
#define S_    2048
#define D_    1024
#define H_    16
#define KV_   4
#define QKB_  16
#define VB_   32
#define NTOK  (B_ * S_)   // 4096
#define L2E_  1.44269504088896f

typedef __attribute__((ext_vector_type(8))) short bshort8;
typedef __attribute__((ext_vector_type(4))) float f32x4;

__device__ __forceinline__ unsigned short bf16_rne(float x) {
    unsigned u = __float_as_uint(x);
    return (unsigned short)((u + 0x7FFFu + ((u >> 16) & 1u)) >> 16);
}
__device__ __forceinline__ unsigned bf16x2_rne(float lo, float hi) {
    return (unsigned)bf16_rne(lo) | ((unsigned)bf16_rne(hi) << 16);
}
__device__ __forceinline__ float sum2bf(unsigned u) {
    return __uint_as_float(u << 16) + __uint_as_float(u & 0xFFFF0000u);
}
__device__ __forceinline__ void stage16(const unsigned short* g, unsigned short* l) {
    __builtin_amdgcn_global_load_lds(
        (const __attribute__((address_space(1))) void*)g,
        (__attribute__((address_space(3))) void*)l, 16, 0, 0);
}

// ---------------- Prep: hs->bf16 (blocks 0..2047) + weight transpose (2048..2287) --
__global__ __launch_bounds__(256) void prep_kernel(
    const float* __restrict__ hs,
    const float* __restrict__ Wq, const float* __restrict__ Wk,
    const float* __restrict__ Wv, const float* __restrict__ Wo,
    unsigned short* __restrict__ hs_b,
    unsigned short* __restrict__ Wcat_t, unsigned short* __restrict__ Wot)
{
    __shared__ float T[64][65];
    const int t = threadIdx.x;
    if (blockIdx.x < 2048) {
        int i = blockIdx.x * 256 + t;
        const float4* s = (const float4*)hs;
        float4 a = s[2 * i], b = s[2 * i + 1];
        uint4 o;
        o.x = bf16x2_rne(a.x, a.y); o.y = bf16x2_rne(a.z, a.w);
        o.z = bf16x2_rne(b.x, b.y); o.w = bf16x2_rne(b.z, b.w);
        ((uint4*)hs_b)[i] = o;
        return;
    }
    const int bid = blockIdx.x - 2048;
    const float* src; unsigned short* dst; int K, N, tk, tn, drow0;
    if (bid < 64)       { src = Wq; dst = Wcat_t; K = 1024; N = 256;  int r = bid;       tk = r & 15; tn = r >> 4; drow0 = 0; }
    else if (bid < 80)  { src = Wk; dst = Wcat_t; K = 1024; N = 64;   int r = bid - 64;  tk = r;      tn = 0;      drow0 = 256; }
    else if (bid < 112) { src = Wv; dst = Wcat_t; K = 1024; N = 128;  int r = bid - 80;  tk = r & 15; tn = r >> 4; drow0 = 320; }
    else                { src = Wo; dst = Wot;    K = 512;  N = 1024; int r = bid - 112; tk = r & 7;  tn = r >> 3; drow0 = 0; }
    const int k0 = tk * 64, n0 = tn * 64;
    const int rr = t >> 4, cc = (t & 15) * 4;
    #pragma unroll
    for (int i = 0; i < 4; ++i) {
        float4 v = *(const float4*)(src + (k0 + rr + i * 16) * N + n0 + cc);
        T[rr + i * 16][cc + 0] = v.x; T[rr + i * 16][cc + 1] = v.y;
        T[rr + i * 16][cc + 2] = v.z; T[rr + i * 16][cc + 3] = v.w;
    }
    __syncthreads();
    const int nloc = t >> 2, kc = (t & 3) * 16;
    unsigned o[8];
    #pragma unroll
    for (int j = 0; j < 8; ++j)
        o[j] = bf16x2_rne(T[kc + 2 * j][nloc], T[kc + 2 * j + 1][nloc]);
    unsigned short* dp = dst + (drow0 + n0 + nloc) * K + k0 + kc;
    uint4 w0; w0.x = o[0]; w0.y = o[1]; w0.z = o[2]; w0.w = o[3];
    uint4 w1; w1.x = o[4]; w1.y = o[5]; w1.z = o[6]; w1.w = o[7];
    *(uint4*)(dp) = w0;
    *(uint4*)(dp + 8) = w1;
}

// ---------------- proj GEMM: 64x64 tile, BK=64, gl_lds + XOR-8 swizzle ---------
// grid (64, 7) = 448 blocks. Wave w: rows w*16, all 64 cols.
__global__ __launch_bounds__(256, 4) void proj_gemm(
    const unsigned short* __restrict__ Ab, const unsigned short* __restrict__ Btb,
    unsigned short* __restrict__ qg, unsigned short* __restrict__ pko,
    unsigned short* __restrict__ pvT)
{
    __shared__ unsigned short As[64 * 64];    // 8 KB
    __shared__ unsigned short Bs[64 * 64];    // 8 KB
    const int tid = threadIdx.x, l = tid & 63, w = tid >> 6;
    const int l15 = l & 15, quad = l >> 4;
    const int m0 = blockIdx.x * 64, n0 = blockIdx.y * 64;
    const int sr8 = l >> 3, sc8 = l & 7;
    f32x4 c[4];
    #pragma unroll
    for (int j = 0; j < 4; ++j) c[j] = (f32x4){0.f, 0.f, 0.f, 0.f};

    for (int k0 = 0; k0 < 1024; k0 += 64) {
        int R0 = w * 8, r0 = R0 + sr8;
        int R1 = 32 + w * 8, r1 = R1 + sr8;
        stage16(Ab  + (m0 + r0) * 1024 + k0 + (sc8 ^ (r0 & 7)) * 8, &As[R0 * 64]);
        stage16(Ab  + (m0 + r1) * 1024 + k0 + (sc8 ^ (r1 & 7)) * 8, &As[R1 * 64]);
        stage16(Btb + (n0 + r0) * 1024 + k0 + (sc8 ^ (r0 & 7)) * 8, &Bs[R0 * 64]);
        stage16(Btb + (n0 + r1) * 1024 + k0 + (sc8 ^ (r1 & 7)) * 8, &Bs[R1 * 64]);
        __syncthreads();
        #pragma unroll
        for (int kh = 0; kh < 2; ++kh) {
            const int arow = w * 16 + l15;
            bshort8 a = *(const bshort8*)&As[arow * 64 + (((kh * 4 + quad) ^ (arow & 7)) * 8)];
            #pragma unroll
            for (int bc = 0; bc < 4; ++bc) {
                const int brow = bc * 16 + l15;
                bshort8 b = *(const bshort8*)&Bs[brow * 64 + (((kh * 4 + quad) ^ (brow & 7)) * 8)];
                c[bc] = __builtin_amdgcn_mfma_f32_16x16x32_bf16(a, b, c[bc], 0, 0, 0);
            }
        }
        __syncthreads();
    }

    const int tok0 = m0 + w * 16 + quad * 4;
    #pragma unroll
    for (int bc = 0; bc < 4; ++bc) {
        f32x4 v = c[bc];
        const int n = n0 + bc * 16 + l15;
        float sg[4];
        #pragma unroll
        for (int r = 0; r < 4; ++r)
            sg[r] = 1.f / (1.f + exp2f(-v[r] * L2E_));
        if (n < 256) {
            const int hh = n >> 4, d = n & 15;
            #pragma unroll
            for (int r = 0; r < 4; ++r) {
                int tok = tok0 + r, bb = tok >> 11, ss = tok & 2047;
                qg[(((bb * 16 + hh) * 2048) + ss) * 16 + d] =
                    bf16_rne(L2E_ * (2.f * sg[r] - 1.f));
            }
        } else if (n < 320) {
            const int j = n - 256, kvv = j >> 4, d = j & 15;
            #pragma unroll
            for (int r = 0; r < 4; ++r) {
                int tok = tok0 + r, bb = tok >> 11, ss = tok & 2047;
                pko[(((bb * 4 + kvv) * 2048) + ss) * 16 + d] = bf16_rne(sg[r]);
            }
        } else {
            const int j = n - 320, kvv = j >> 5, d = j & 31;
            const int bb = tok0 >> 11, ss = tok0 & 2047;
            const int tl = ss >> 6, ccol = ss & 63;
            uint2 wv; wv.x = bf16x2_rne(sg[0], sg[1]); wv.y = bf16x2_rne(sg[2], sg[3]);
            *(uint2*)(pvT + ((((bb * 4 + kvv) * 32) + tl) * 32 + d) * 64 + ccol) = wv;
        }
    }
}

// ---------------- outproj GEMM: 64x128 tile, BK=64, gl_lds + XOR-8 swizzle -----
// grid (64, 8) = 512 blocks (2/CU). Wave (wr,wc): rows wr*32 (2), cols wc*64 (4).
__global__ __launch_bounds__(256, 2) void outproj_gemm(
    const unsigned short* __restrict__ Ab, const unsigned short* __restrict__ Btb,
    float* __restrict__ out)
{
    __shared__ unsigned short As[64 * 64];    //  8 KB
    __shared__ unsigned short Bs[128 * 64];   // 16 KB
    const int tid = threadIdx.x, l = tid & 63, w = tid >> 6;
    const int l15 = l & 15, quad = l >> 4;
    const int m0 = blockIdx.x * 64, n0 = blockIdx.y * 128;
    const int wr = w & 1, wc = w >> 1;
    const int sr8 = l >> 3, sc8 = l & 7;
    f32x4 c[2][4];
    #pragma unroll
    for (int i = 0; i < 2; ++i)
        #pragma unroll
        for (int j = 0; j < 4; ++j) c[i][j] = (f32x4){0.f, 0.f, 0.f, 0.f};

    for (int k0 = 0; k0 < 512; k0 += 64) {
        #pragma unroll
        for (int j = 0; j < 2; ++j) {
            int R = w * 16 + j * 8, r = R + sr8;
            stage16(Ab + (m0 + r) * 512 + k0 + (sc8 ^ (r & 7)) * 8, &As[R * 64]);
        }
        #pragma unroll
        for (int j = 0; j < 4; ++j) {
            int R = j * 32 + w * 8, r = R + sr8;
            stage16(Btb + (n0 + r) * 512 + k0 + (sc8 ^ (r & 7)) * 8, &Bs[R * 64]);
        }
        __syncthreads();
        #pragma unroll
        for (int kh = 0; kh < 2; ++kh) {
            bshort8 a[2], b[4];
            #pragma unroll
            for (int ar = 0; ar < 2; ++ar) {
                int row = wr * 32 + ar * 16 + l15;
                a[ar] = *(const bshort8*)&As[row * 64 + (((kh * 4 + quad) ^ (row & 7)) * 8)];
            }
            #pragma unroll
            for (int bc = 0; bc < 4; ++bc) {
                int row = wc * 64 + bc * 16 + l15;
                b[bc] = *(const bshort8*)&Bs[row * 64 + (((kh * 4 + quad) ^ (row & 7)) * 8)];
            }
            #pragma unroll
            for (int ar = 0; ar < 2; ++ar)
                #pragma unroll
                for (int bc = 0; bc < 4; ++bc)
                    c[ar][bc] = __builtin_amdgcn_mfma_f32_16x16x32_bf16(a[ar], b[bc], c[ar][bc], 0, 0, 0);
        }
        __syncthreads();
    }

    #pragma unroll
    for (int ar = 0; ar < 2; ++ar)
        #pragma unroll
        for (int bc = 0; bc < 4; ++bc) {
            f32x4 v = c[ar][bc];
            const int col = n0 + wc * 64 + bc * 16 + l15;
            const int r0 = m0 + wr * 32 + ar * 16 + quad * 4;
            #pragma unroll
            for (int r = 0; r < 4; ++r)
                out[(r0 + r) * D_ + col] = v[r];
        }
}

// ---------------- Attention: barrier-free MFMA flash ----------------
// Per wave: 16 queries, all key tiles. K and V fragments read directly from
// global (L2-resident); qg row read directly from global. Only LDS use is the
// wave-private P repack (C-layout -> B-operand), ordered by lgkmcnt within
// the wave -> ZERO __syncthreads in the whole kernel.
struct AttnLDS {
    unsigned short P[4][16][88];   // 11 KB, stride 88: ~2-way max on r/w
};

__global__ __launch_bounds__(256, 4) void attn_kernel(
    const unsigned short* __restrict__ qg_g, const unsigned short* __restrict__ pk_g,
    const unsigned short* __restrict__ pvT_g, const float* __restrict__ e0,
    const float* __restrict__ e1, unsigned short* __restrict__ xo)
{
    __shared__ AttnLDS L;
    const int tid = threadIdx.x, l = tid & 63, wq = tid >> 6;
    const int l15 = l & 15, quad = l >> 4;
    // balanced mapping: CU's 4 resident blocks (g, g+256, g+512, g+768) get
    // qt {r, 31-r, 8+r, 23-r} -> 66 tile-iters per CU, uniform.
    const int g = blockIdx.x;
    const int idx = g & 255, kg = g >> 8;
    const int bh = idx & 31, rr = idx >> 5;
    int qt;
    if      (kg == 0) qt = rr;
    else if (kg == 1) qt = 31 - rr;
    else if (kg == 2) qt = 8 + rr;
    else              qt = 23 - rr;
    const int b = bh >> 4, h = bh & 15, kv = h >> 2;
    const int qbase = qt * 64;
    const unsigned short* pkb = pk_g + ((b * 4 + kv) * 2048) * 16;
    const unsigned short* pvb = pvT_g + (b * 4 + kv) * 65536;  // [tile][vd32][key64]
    const unsigned short* qgb = qg_g + ((b * 16 + h) * 2048) * 16;

    const f32x4 zero4 = {0.f, 0.f, 0.f, 0.f};
    const bshort8 zero8 = {0, 0, 0, 0, 0, 0, 0, 0};

    // q row straight from global: 32 B; fragment select by quad.
    const unsigned short* qrow = qgb + (qbase + wq * 16 + l15) * 16;
    uint4 qu0 = *(const uint4*)qrow;
    uint4 qu1 = *(const uint4*)(qrow + 8);
    float s = sum2bf(qu0.x) + sum2bf(qu0.y) + sum2bf(qu0.z) + sum2bf(qu0.w)
            + sum2bf(qu1.x) + sum2bf(qu1.y) + sum2bf(qu1.z) + sum2bf(qu1.w);
    bshort8 qfrag = zero8;
    if (quad == 0)      qfrag = __builtin_bit_cast(bshort8, qu0);
    else if (quad == 1) qfrag = __builtin_bit_cast(bshort8, qu1);
    else if (quad == 2) qfrag[0] = (short)bf16_rne(-8.f * L2E_ - 0.5f * s);

    bshort8 kone = zero8; kone[0] = (short)0x3F80;   // bf16 1.0 (k=16 slot)

    f32x4 acc0 = zero4, acc1 = zero4;
    float lsum = 0.f;

    for (int t = 0; t < qt; ++t) {
        const int t0 = t * 64;
        f32x4 sc[4];
        #pragma unroll
        for (int ks = 0; ks < 4; ++ks) {
            bshort8 kf;
            if (quad < 2)       kf = *(const bshort8*)(pkb + (t0 + ks * 16 + l15) * 16 + quad * 8);
            else if (quad == 2) kf = kone;
            else                kf = zero8;
            sc[ks] = __builtin_amdgcn_mfma_f32_16x16x32_bf16(kf, qfrag, zero4, 0, 0, 0);
        }
        const unsigned short* vb = pvb + t * 2048 + l15 * 64 + quad * 8;
        bshort8 vlo0 = *(const bshort8*)(vb);
        bshort8 vlo1 = *(const bshort8*)(vb + 32);
        bshort8 vhi0 = *(const bshort8*)(vb + 1024);
        bshort8 vhi1 = *(const bshort8*)(vb + 1056);

        #pragma unroll
        for (int ks = 0; ks < 4; ++ks) {
            float p0 = exp2f(sc[ks][0]), p1 = exp2f(sc[ks][1]);
            float p2 = exp2f(sc[ks][2]), p3 = exp2f(sc[ks][3]);
            lsum += p0 + p1 + p2 + p3;
            uint2 wv; wv.x = bf16x2_rne(p0, p1); wv.y = bf16x2_rne(p2, p3);
            *(uint2*)&L.P[wq][l15][ks * 16 + quad * 4] = wv;
        }
        {
            bshort8 pf0 = *(const bshort8*)&L.P[wq][l15][quad * 8];
            bshort8 pf1 = *(const bshort8*)&L.P[wq][l15][32 + quad * 8];
            acc0 = __builtin_amdgcn_mfma_f32_16x16x32_bf16(vlo0, pf0, acc0, 0, 0, 0);
            acc1 = __builtin_amdgcn_mfma_f32_16x16x32_bf16(vhi0, pf0, acc1, 0, 0, 0);
            acc0 = __builtin_amdgcn_mfma_f32_16x16x32_bf16(vlo1, pf1, acc0, 0, 0, 0);
            acc1 = __builtin_amdgcn_mfma_f32_16x16x32_bf16(vhi1, pf1, acc1, 0, 0, 0);
        }
    }

    {   // peeled diagonal tile t = qt (causal mask)
        const int t0 = qt * 64;
        const int q_lane = qbase + wq * 16 + l15;
        f32x4 sc[4];
        #pragma unroll
        for (int ks = 0; ks < 4; ++ks) {
            bshort8 kf;
            if (quad < 2)       kf = *(const bshort8*)(pkb + (t0 + ks * 16 + l15) * 16 + quad * 8);
            else if (quad == 2) kf = kone;
            else                kf = zero8;
            sc[ks] = __builtin_amdgcn_mfma_f32_16x16x32_bf16(kf, qfrag, zero4, 0, 0, 0);
        }
        const unsigned short* vb = pvb + qt * 2048 + l15 * 64 + quad * 8;
        bshort8 vlo0 = *(const bshort8*)(vb);
        bshort8 vlo1 = *(const bshort8*)(vb + 32);
        bshort8 vhi0 = *(const bshort8*)(vb + 1024);
        bshort8 vhi1 = *(const bshort8*)(vb + 1056);

        #pragma unroll
        for (int ks = 0; ks < 4; ++ks) {
            float pv0[4];
            #pragma unroll
            for (int r = 0; r < 4; ++r) {
                const int tg = t0 + ks * 16 + quad * 4 + r;
                float pp = (tg <= q_lane) ? exp2f(sc[ks][r]) : 0.f;
                lsum += pp; pv0[r] = pp;
            }
            uint2 wv; wv.x = bf16x2_rne(pv0[0], pv0[1]); wv.y = bf16x2_rne(pv0[2], pv0[3]);
            *(uint2*)&L.P[wq][l15][ks * 16 + quad * 4] = wv;
        }
        {
            bshort8 pf0 = *(const bshort8*)&L.P[wq][l15][quad * 8];
            bshort8 pf1 = *(const bshort8*)&L.P[wq][l15][32 + quad * 8];
            acc0 = __builtin_amdgcn_mfma_f32_16x16x32_bf16(vlo0, pf0, acc0, 0, 0, 0);
            acc1 = __builtin_amdgcn_mfma_f32_16x16x32_bf16(vhi0, pf0, acc1, 0, 0, 0);
            acc0 = __builtin_amdgcn_mfma_f32_16x16x32_bf16(vlo1, pf1, acc0, 0, 0, 0);
            acc1 = __builtin_amdgcn_mfma_f32_16x16x32_bf16(vhi1, pf1, acc1, 0, 0, 0);
        }
    }

    lsum += __shfl_xor(lsum, 16);
    lsum += __shfl_xor(lsum, 32);
    const float inv = 1.f / lsum;

    float e0v[8], dEv[8];
    #pragma unroll
    for (int vs = 0; vs < 2; ++vs)
        #pragma unroll
        for (int r = 0; r < 4; ++r) {
            int idx2 = h * 32 + vs * 16 + quad * 4 + r;
            float a = e0[idx2];
            e0v[vs * 4 + r] = a; dEv[vs * 4 + r] = e1[idx2] - a;
        }
    const int tok = b * 2048 + qbase + wq * 16 + l15;
    float o0[4], o1[4];
    #pragma unroll
    for (int r = 0; r < 4; ++r) {
        o0[r] = e0v[r]     + dEv[r]     * (acc0[r] * inv);
        o1[r] = e0v[4 + r] + dEv[4 + r] * (acc1[r] * inv);
    }
    uint2 w0; w0.x = bf16x2_rne(o0[0], o0[1]); w0.y = bf16x2_rne(o0[2], o0[3]);
    uint2 w1; w1.x = bf16x2_rne(o1[0], o1[1]); w1.y = bf16x2_rne(o1[2], o1[3]);
    *(uint2*)(xo + tok * 512 + h * 32 + quad * 4)      = w0;
    *(uint2*)(xo + tok * 512 + h * 32 + 16 + quad * 4) = w1;
}

extern "C" void kernel_launch(void* const* d_in, const int* in_sizes, int n_in,
                              void* d_out, int out_size, void* d_ws, size_t ws_size,
                              hipStream_t stream)
{
    const float* hs = (const float*)d_in[0];
    const float* Wq = (const float*)d_in[1];
    const float* Wk = (const float*)d_in[2];
    const float* Wv = (const float*)d_in[3];
    const float* Wo = (const float*)d_in[4];
    const float* e0 = (const float*)d_in[5];
    const float* e1 = (const float*)d_in[6];
    float* out = (float*)d_out;

    char* ws = (char*)d_ws;
    unsigned short* hs_b   = (unsigned short*)(ws);
    unsigned short* xo     = (unsigned short*)(ws);
    unsigned short* Wcat_t = (unsigned short*)(ws + 8388608);
    unsigned short* Wot    = (unsigned short*)(ws + 8388608 + 917504);
    unsigned short* qg     = (unsigned short*)(ws + 10354688);
    unsigned short* pk     = (unsigned short*)(ws + 12451840);
    unsigned short* pvT    = (unsigned short*)(ws + 12976128);

    prep_kernel<<<2288, 256, 0, stream>>>(hs, Wq, Wk, Wv, Wo, hs_b, Wcat_t, Wot);
    proj_gemm<<<dim3(64, 7), 256, 0, stream>>>(hs_b, Wcat_t, qg, pk, pvT);
    attn_kernel<<<1024, 256, 0, stream>>>(qg, pk, pvT, e0, e1, xo);
    outproj_gemm<<<dim3(64, 8), 256, 0, stream>>>(xo, Wot, out);
}

// Round 8
// 145.991 us; speedup vs baseline: 1.0868x; 1.0868x over previous
//
#include <hip/hip_runtime.h>
#include <hip/hip_bf16.h>

#define B_    2
#define S_    2048
#define D_    1024
#define H_    16
#define KV_   4
#define QKB_  16
#define VB_   32
#define NTOK  (B_ * S_)   // 4096
#define L2E_  1.44269504088896f

typedef __attribute__((ext_vector_type(8))) short bshort8;
typedef __attribute__((ext_vector_type(4))) float f32x4;

__device__ __forceinline__ unsigned short bf16_rne(float x) {
    unsigned u = __float_as_uint(x);
    return (unsigned short)((u + 0x7FFFu + ((u >> 16) & 1u)) >> 16);
}
__device__ __forceinline__ unsigned bf16x2_rne(float lo, float hi) {
    return (unsigned)bf16_rne(lo) | ((unsigned)bf16_rne(hi) << 16);
}
__device__ __forceinline__ float sum2bf(unsigned u) {
    return __uint_as_float(u << 16) + __uint_as_float(u & 0xFFFF0000u);
}
__device__ __forceinline__ void stage16(const unsigned short* g, unsigned short* l) {
    __builtin_amdgcn_global_load_lds(
        (const __attribute__((address_space(1))) void*)g,
        (__attribute__((address_space(3))) void*)l, 16, 0, 0);
}

// ---------------- Prep: hs->bf16 (blocks 0..2047) + weight transpose (2048..2287) --
__global__ __launch_bounds__(256) void prep_kernel(
    const float* __restrict__ hs,
    const float* __restrict__ Wq, const float* __restrict__ Wk,
    const float* __restrict__ Wv, const float* __restrict__ Wo,
    unsigned short* __restrict__ hs_b,
    unsigned short* __restrict__ Wcat_t, unsigned short* __restrict__ Wot)
{
    __shared__ float T[64][65];
    const int t = threadIdx.x;
    if (blockIdx.x < 2048) {
        int i = blockIdx.x * 256 + t;
        const float4* s = (const float4*)hs;
        float4 a = s[2 * i], b = s[2 * i + 1];
        uint4 o;
        o.x = bf16x2_rne(a.x, a.y); o.y = bf16x2_rne(a.z, a.w);
        o.z = bf16x2_rne(b.x, b.y); o.w = bf16x2_rne(b.z, b.w);
        ((uint4*)hs_b)[i] = o;
        return;
    }
    const int bid = blockIdx.x - 2048;
    const float* src; unsigned short* dst; int K, N, tk, tn, drow0;
    if (bid < 64)       { src = Wq; dst = Wcat_t; K = 1024; N = 256;  int r = bid;       tk = r & 15; tn = r >> 4; drow0 = 0; }
    else if (bid < 80)  { src = Wk; dst = Wcat_t; K = 1024; N = 64;   int r = bid - 64;  tk = r;      tn = 0;      drow0 = 256; }
    else if (bid < 112) { src = Wv; dst = Wcat_t; K = 1024; N = 128;  int r = bid - 80;  tk = r & 15; tn = r >> 4; drow0 = 320; }
    else                { src = Wo; dst = Wot;    K = 512;  N = 1024; int r = bid - 112; tk = r & 7;  tn = r >> 3; drow0 = 0; }
    const int k0 = tk * 64, n0 = tn * 64;
    const int rr = t >> 4, cc = (t & 15) * 4;
    #pragma unroll
    for (int i = 0; i < 4; ++i) {
        float4 v = *(const float4*)(src + (k0 + rr + i * 16) * N + n0 + cc);
        T[rr + i * 16][cc + 0] = v.x; T[rr + i * 16][cc + 1] = v.y;
        T[rr + i * 16][cc + 2] = v.z; T[rr + i * 16][cc + 3] = v.w;
    }
    __syncthreads();
    const int nloc = t >> 2, kc = (t & 3) * 16;
    unsigned o[8];
    #pragma unroll
    for (int j = 0; j < 8; ++j)
        o[j] = bf16x2_rne(T[kc + 2 * j][nloc], T[kc + 2 * j + 1][nloc]);
    unsigned short* dp = dst + (drow0 + n0 + nloc) * K + k0 + kc;
    uint4 w0; w0.x = o[0]; w0.y = o[1]; w0.z = o[2]; w0.w = o[3];
    uint4 w1; w1.x = o[4]; w1.y = o[5]; w1.z = o[6]; w1.w = o[7];
    *(uint4*)(dp) = w0;
    *(uint4*)(dp + 8) = w1;
}

// ---------------- proj GEMM: 64x64 tile, BK=64, gl_lds + XOR-8 swizzle ---------
__global__ __launch_bounds__(256, 4) void proj_gemm(
    const unsigned short* __restrict__ Ab, const unsigned short* __restrict__ Btb,
    unsigned short* __restrict__ qg, unsigned short* __restrict__ pko,
    unsigned short* __restrict__ pvT)
{
    __shared__ unsigned short As[64 * 64];    // 8 KB
    __shared__ unsigned short Bs[64 * 64];    // 8 KB
    const int tid = threadIdx.x, l = tid & 63, w = tid >> 6;
    const int l15 = l & 15, quad = l >> 4;
    const int m0 = blockIdx.x * 64, n0 = blockIdx.y * 64;
    const int sr8 = l >> 3, sc8 = l & 7;
    f32x4 c[4];
    #pragma unroll
    for (int j = 0; j < 4; ++j) c[j] = (f32x4){0.f, 0.f, 0.f, 0.f};

    for (int k0 = 0; k0 < 1024; k0 += 64) {
        int R0 = w * 8, r0 = R0 + sr8;
        int R1 = 32 + w * 8, r1 = R1 + sr8;
        stage16(Ab  + (m0 + r0) * 1024 + k0 + (sc8 ^ (r0 & 7)) * 8, &As[R0 * 64]);
        stage16(Ab  + (m0 + r1) * 1024 + k0 + (sc8 ^ (r1 & 7)) * 8, &As[R1 * 64]);
        stage16(Btb + (n0 + r0) * 1024 + k0 + (sc8 ^ (r0 & 7)) * 8, &Bs[R0 * 64]);
        stage16(Btb + (n0 + r1) * 1024 + k0 + (sc8 ^ (r1 & 7)) * 8, &Bs[R1 * 64]);
        __syncthreads();
        #pragma unroll
        for (int kh = 0; kh < 2; ++kh) {
            const int arow = w * 16 + l15;
            bshort8 a = *(const bshort8*)&As[arow * 64 + (((kh * 4 + quad) ^ (arow & 7)) * 8)];
            #pragma unroll
            for (int bc = 0; bc < 4; ++bc) {
                const int brow = bc * 16 + l15;
                bshort8 b = *(const bshort8*)&Bs[brow * 64 + (((kh * 4 + quad) ^ (brow & 7)) * 8)];
                c[bc] = __builtin_amdgcn_mfma_f32_16x16x32_bf16(a, b, c[bc], 0, 0, 0);
            }
        }
        __syncthreads();
    }

    const int tok0 = m0 + w * 16 + quad * 4;
    #pragma unroll
    for (int bc = 0; bc < 4; ++bc) {
        f32x4 v = c[bc];
        const int n = n0 + bc * 16 + l15;
        float sg[4];
        #pragma unroll
        for (int r = 0; r < 4; ++r)
            sg[r] = 1.f / (1.f + exp2f(-v[r] * L2E_));
        if (n < 256) {
            const int hh = n >> 4, d = n & 15;
            #pragma unroll
            for (int r = 0; r < 4; ++r) {
                int tok = tok0 + r, bb = tok >> 11, ss = tok & 2047;
                qg[(((bb * 16 + hh) * 2048) + ss) * 16 + d] =
                    bf16_rne(L2E_ * (2.f * sg[r] - 1.f));
            }
        } else if (n < 320) {
            const int j = n - 256, kvv = j >> 4, d = j & 15;
            #pragma unroll
            for (int r = 0; r < 4; ++r) {
                int tok = tok0 + r, bb = tok >> 11, ss = tok & 2047;
                pko[(((bb * 4 + kvv) * 2048) + ss) * 16 + d] = bf16_rne(sg[r]);
            }
        } else {
            const int j = n - 320, kvv = j >> 5, d = j & 31;
            const int bb = tok0 >> 11, ss = tok0 & 2047;
            const int tl = ss >> 6, ccol = ss & 63;
            uint2 wv; wv.x = bf16x2_rne(sg[0], sg[1]); wv.y = bf16x2_rne(sg[2], sg[3]);
            *(uint2*)(pvT + ((((bb * 4 + kvv) * 32) + tl) * 32 + d) * 64 + ccol) = wv;
        }
    }
}

// ---------------- outproj GEMM: 64x128 tile, BK=64, gl_lds + XOR-8 swizzle -----
__global__ __launch_bounds__(256, 2) void outproj_gemm(
    const unsigned short* __restrict__ Ab, const unsigned short* __restrict__ Btb,
    float* __restrict__ out)
{
    __shared__ unsigned short As[64 * 64];    //  8 KB
    __shared__ unsigned short Bs[128 * 64];   // 16 KB
    const int tid = threadIdx.x, l = tid & 63, w = tid >> 6;
    const int l15 = l & 15, quad = l >> 4;
    const int m0 = blockIdx.x * 64, n0 = blockIdx.y * 128;
    const int wr = w & 1, wc = w >> 1;
    const int sr8 = l >> 3, sc8 = l & 7;
    f32x4 c[2][4];
    #pragma unroll
    for (int i = 0; i < 2; ++i)
        #pragma unroll
        for (int j = 0; j < 4; ++j) c[i][j] = (f32x4){0.f, 0.f, 0.f, 0.f};

    for (int k0 = 0; k0 < 512; k0 += 64) {
        #pragma unroll
        for (int j = 0; j < 2; ++j) {
            int R = w * 16 + j * 8, r = R + sr8;
            stage16(Ab + (m0 + r) * 512 + k0 + (sc8 ^ (r & 7)) * 8, &As[R * 64]);
        }
        #pragma unroll
        for (int j = 0; j < 4; ++j) {
            int R = j * 32 + w * 8, r = R + sr8;
            stage16(Btb + (n0 + r) * 512 + k0 + (sc8 ^ (r & 7)) * 8, &Bs[R * 64]);
        }
        __syncthreads();
        #pragma unroll
        for (int kh = 0; kh < 2; ++kh) {
            bshort8 a[2], b[4];
            #pragma unroll
            for (int ar = 0; ar < 2; ++ar) {
                int row = wr * 32 + ar * 16 + l15;
                a[ar] = *(const bshort8*)&As[row * 64 + (((kh * 4 + quad) ^ (row & 7)) * 8)];
            }
            #pragma unroll
            for (int bc = 0; bc < 4; ++bc) {
                int row = wc * 64 + bc * 16 + l15;
                b[bc] = *(const bshort8*)&Bs[row * 64 + (((kh * 4 + quad) ^ (row & 7)) * 8)];
            }
            #pragma unroll
            for (int ar = 0; ar < 2; ++ar)
                #pragma unroll
                for (int bc = 0; bc < 4; ++bc)
                    c[ar][bc] = __builtin_amdgcn_mfma_f32_16x16x32_bf16(a[ar], b[bc], c[ar][bc], 0, 0, 0);
        }
        __syncthreads();
    }

    #pragma unroll
    for (int ar = 0; ar < 2; ++ar)
        #pragma unroll
        for (int bc = 0; bc < 4; ++bc) {
            f32x4 v = c[ar][bc];
            const int col = n0 + wc * 64 + bc * 16 + l15;
            const int r0 = m0 + wr * 32 + ar * 16 + quad * 4;
            #pragma unroll
            for (int r = 0; r < 4; ++r)
                out[(r0 + r) * D_ + col] = v[r];
        }
}

// ---------------- Attention: barrier-free MFMA flash, register-double-buffered --
// Per wave: 16 queries, all key tiles. K/V fragments prefetched from global
// into a second register set one iteration ahead (load->use distance = one
// full tile of exp/pack/MFMA work hides L2 latency). Only LDS use is the
// wave-private P repack; ZERO __syncthreads.
__global__ __launch_bounds__(256, 4) void attn_kernel(
    const unsigned short* __restrict__ qg_g, const unsigned short* __restrict__ pk_g,
    const unsigned short* __restrict__ pvT_g, const float* __restrict__ e0,
    const float* __restrict__ e1, unsigned short* __restrict__ xo)
{
    __shared__ unsigned short P[4][16][88];   // 11 KB, stride 88: ~2-way max
    const int tid = threadIdx.x, l = tid & 63, wq = tid >> 6;
    const int l15 = l & 15, quad = l >> 4;
    // balanced mapping: CU's 4 resident blocks (g, g+256, g+512, g+768) get
    // qt {r, 31-r, 8+r, 23-r} -> 66 tile-iters per CU, uniform.
    const int g = blockIdx.x;
    const int idx = g & 255, kg = g >> 8;
    const int bh = idx & 31, rr = idx >> 5;
    int qt;
    if      (kg == 0) qt = rr;
    else if (kg == 1) qt = 31 - rr;
    else if (kg == 2) qt = 8 + rr;
    else              qt = 23 - rr;
    const int b = bh >> 4, h = bh & 15, kv = h >> 2;
    const int qbase = qt * 64;
    const unsigned short* pkb = pk_g + ((b * 4 + kv) * 2048) * 16;
    const unsigned short* pvb = pvT_g + (b * 4 + kv) * 65536;  // [tile][vd32][key64]
    const unsigned short* qgb = qg_g + ((b * 16 + h) * 2048) * 16;

    const f32x4 zero4 = {0.f, 0.f, 0.f, 0.f};
    const bshort8 zero8 = {0, 0, 0, 0, 0, 0, 0, 0};

    // q row straight from global: 32 B; fragment select by quad.
    const unsigned short* qrow = qgb + (qbase + wq * 16 + l15) * 16;
    uint4 qu0 = *(const uint4*)qrow;
    uint4 qu1 = *(const uint4*)(qrow + 8);
    float s = sum2bf(qu0.x) + sum2bf(qu0.y) + sum2bf(qu0.z) + sum2bf(qu0.w)
            + sum2bf(qu1.x) + sum2bf(qu1.y) + sum2bf(qu1.z) + sum2bf(qu1.w);
    bshort8 qfrag = zero8;
    if (quad == 0)      qfrag = __builtin_bit_cast(bshort8, qu0);
    else if (quad == 1) qfrag = __builtin_bit_cast(bshort8, qu1);
    else if (quad == 2) qfrag[0] = (short)bf16_rne(-8.f * L2E_ - 0.5f * s);

    bshort8 kone = zero8; kone[0] = (short)0x3F80;   // bf16 1.0 (k=16 slot)

    f32x4 acc0 = zero4, acc1 = zero4;
    float lsum = 0.f;

    bshort8 kc[4], vc[4], kn[4], vn[4];
    // load tile 0
    if (quad < 2) {
        #pragma unroll
        for (int ks = 0; ks < 4; ++ks)
            kc[ks] = *(const bshort8*)(pkb + (ks * 16 + l15) * 16 + quad * 8);
    }
    {
        const unsigned short* vb = pvb + l15 * 64 + quad * 8;
        vc[0] = *(const bshort8*)(vb);
        vc[1] = *(const bshort8*)(vb + 32);
        vc[2] = *(const bshort8*)(vb + 1024);
        vc[3] = *(const bshort8*)(vb + 1056);
    }

    #pragma unroll 2
    for (int t = 0; t < qt; ++t) {
        // ---- prefetch tile t+1 into the shadow set ----
        if (quad < 2) {
            #pragma unroll
            for (int ks = 0; ks < 4; ++ks)
                kn[ks] = *(const bshort8*)(pkb + ((t + 1) * 64 + ks * 16 + l15) * 16 + quad * 8);
        }
        {
            const unsigned short* vb = pvb + (t + 1) * 2048 + l15 * 64 + quad * 8;
            vn[0] = *(const bshort8*)(vb);
            vn[1] = *(const bshort8*)(vb + 32);
            vn[2] = *(const bshort8*)(vb + 1024);
            vn[3] = *(const bshort8*)(vb + 1056);
        }
        // ---- compute tile t from the current set ----
        f32x4 sc[4];
        #pragma unroll
        for (int ks = 0; ks < 4; ++ks) {
            bshort8 kf;
            if (quad < 2)       kf = kc[ks];
            else if (quad == 2) kf = kone;
            else                kf = zero8;
            sc[ks] = __builtin_amdgcn_mfma_f32_16x16x32_bf16(kf, qfrag, zero4, 0, 0, 0);
        }
        #pragma unroll
        for (int ks = 0; ks < 4; ++ks) {
            float p0 = exp2f(sc[ks][0]), p1 = exp2f(sc[ks][1]);
            float p2 = exp2f(sc[ks][2]), p3 = exp2f(sc[ks][3]);
            lsum += p0 + p1 + p2 + p3;
            uint2 wv; wv.x = bf16x2_rne(p0, p1); wv.y = bf16x2_rne(p2, p3);
            *(uint2*)&P[wq][l15][ks * 16 + quad * 4] = wv;
        }
        {
            bshort8 pf0 = *(const bshort8*)&P[wq][l15][quad * 8];
            bshort8 pf1 = *(const bshort8*)&P[wq][l15][32 + quad * 8];
            acc0 = __builtin_amdgcn_mfma_f32_16x16x32_bf16(vc[0], pf0, acc0, 0, 0, 0);
            acc1 = __builtin_amdgcn_mfma_f32_16x16x32_bf16(vc[2], pf0, acc1, 0, 0, 0);
            acc0 = __builtin_amdgcn_mfma_f32_16x16x32_bf16(vc[1], pf1, acc0, 0, 0, 0);
            acc1 = __builtin_amdgcn_mfma_f32_16x16x32_bf16(vc[3], pf1, acc1, 0, 0, 0);
        }
        // ---- rotate ----
        #pragma unroll
        for (int i = 0; i < 4; ++i) { kc[i] = kn[i]; vc[i] = vn[i]; }
    }

    {   // peeled diagonal tile t = qt (causal mask)
        const int t0 = qt * 64;
        const int q_lane = qbase + wq * 16 + l15;
        f32x4 sc[4];
        #pragma unroll
        for (int ks = 0; ks < 4; ++ks) {
            bshort8 kf;
            if (quad < 2)       kf = kc[ks];
            else if (quad == 2) kf = kone;
            else                kf = zero8;
            sc[ks] = __builtin_amdgcn_mfma_f32_16x16x32_bf16(kf, qfrag, zero4, 0, 0, 0);
        }
        #pragma unroll
        for (int ks = 0; ks < 4; ++ks) {
            float pv0[4];
            #pragma unroll
            for (int r = 0; r < 4; ++r) {
                const int tg = t0 + ks * 16 + quad * 4 + r;
                float pp = (tg <= q_lane) ? exp2f(sc[ks][r]) : 0.f;
                lsum += pp; pv0[r] = pp;
            }
            uint2 wv; wv.x = bf16x2_rne(pv0[0], pv0[1]); wv.y = bf16x2_rne(pv0[2], pv0[3]);
            *(uint2*)&P[wq][l15][ks * 16 + quad * 4] = wv;
        }
        {
            bshort8 pf0 = *(const bshort8*)&P[wq][l15][quad * 8];
            bshort8 pf1 = *(const bshort8*)&P[wq][l15][32 + quad * 8];
            acc0 = __builtin_amdgcn_mfma_f32_16x16x32_bf16(vc[0], pf0, acc0, 0, 0, 0);
            acc1 = __builtin_amdgcn_mfma_f32_16x16x32_bf16(vc[2], pf0, acc1, 0, 0, 0);
            acc0 = __builtin_amdgcn_mfma_f32_16x16x32_bf16(vc[1], pf1, acc0, 0, 0, 0);
            acc1 = __builtin_amdgcn_mfma_f32_16x16x32_bf16(vc[3], pf1, acc1, 0, 0, 0);
        }
    }

    lsum += __shfl_xor(lsum, 16);
    lsum += __shfl_xor(lsum, 32);
    const float inv = 1.f / lsum;

    float e0v[8], dEv[8];
    #pragma unroll
    for (int vs = 0; vs < 2; ++vs)
        #pragma unroll
        for (int r = 0; r < 4; ++r) {
            int idx2 = h * 32 + vs * 16 + quad * 4 + r;
            float a = e0[idx2];
            e0v[vs * 4 + r] = a; dEv[vs * 4 + r] = e1[idx2] - a;
        }
    const int tok = b * 2048 + qbase + wq * 16 + l15;
    float o0[4], o1[4];
    #pragma unroll
    for (int r = 0; r < 4; ++r) {
        o0[r] = e0v[r]     + dEv[r]     * (acc0[r] * inv);
        o1[r] = e0v[4 + r] + dEv[4 + r] * (acc1[r] * inv);
    }
    uint2 w0; w0.x = bf16x2_rne(o0[0], o0[1]); w0.y = bf16x2_rne(o0[2], o0[3]);
    uint2 w1; w1.x = bf16x2_rne(o1[0], o1[1]); w1.y = bf16x2_rne(o1[2], o1[3]);
    *(uint2*)(xo + tok * 512 + h * 32 + quad * 4)      = w0;
    *(uint2*)(xo + tok * 512 + h * 32 + 16 + quad * 4) = w1;
}

extern "C" void kernel_launch(void* const* d_in, const int* in_sizes, int n_in,
                              void* d_out, int out_size, void* d_ws, size_t ws_size,
                              hipStream_t stream)
{
    const float* hs = (const float*)d_in[0];
    const float* Wq = (const float*)d_in[1];
    const float* Wk = (const float*)d_in[2];
    const float* Wv = (const float*)d_in[3];
    const float* Wo = (const float*)d_in[4];
    const float* e0 = (const float*)d_in[5];
    const float* e1 = (const float*)d_in[6];
    float* out = (float*)d_out;

    char* ws = (char*)d_ws;
    unsigned short* hs_b   = (unsigned short*)(ws);
    unsigned short* xo     = (unsigned short*)(ws);
    unsigned short* Wcat_t = (unsigned short*)(ws + 8388608);
    unsigned short* Wot    = (unsigned short*)(ws + 8388608 + 917504);
    unsigned short* qg     = (unsigned short*)(ws + 10354688);
    unsigned short* pk     = (unsigned short*)(ws + 12451840);
    unsigned short* pvT    = (unsigned short*)(ws + 12976128);

    prep_kernel<<<2288, 256, 0, stream>>>(hs, Wq, Wk, Wv, Wo, hs_b, Wcat_t, Wot);
    proj_gemm<<<dim3(64, 7), 256, 0, stream>>>(hs_b, Wcat_t, qg, pk, pvT);
    attn_kernel<<<1024, 256, 0, stream>>>(qg, pk, pvT, e0, e1, xo);
    outproj_gemm<<<dim3(64, 8), 256, 0, stream>>>(xo, Wot, out);
}